// Round 12
// baseline (400.613 us; speedup 1.0000x reference)
//
#include <hip/hip_runtime.h>
#include <hip/hip_bf16.h>
#include <cstdint>
#include <cstddef>

#define T_TOK 8192
#define DIM   1024
#define HID   2048
#define NE    8
#define CAP   2816   // 22 tiles of 128; expected count ~2048, +19 sigma margin

typedef __attribute__((ext_vector_type(8))) short bf16x8;
typedef __attribute__((ext_vector_type(4))) float f32x4;
using bf16 = __hip_bfloat16;

__device__ __forceinline__ void gload16(const bf16* g, bf16* l) {
    __builtin_amdgcn_global_load_lds(
        (const __attribute__((address_space(1))) unsigned int*)(g),
        (__attribute__((address_space(3))) unsigned int*)(l), 16, 0, 0);
}
__device__ __forceinline__ float b2f(unsigned short u) {
    return __uint_as_float(((unsigned int)u) << 16);
}
#define MFMA16(a, b, c) __builtin_amdgcn_mfma_f32_16x16x32_bf16((a), (b), (c), 0, 0, 0)

// ---- fused per-expert transpose+convert: [E][R][C] f32 -> [E][C][R] bf16 ----
__global__ __launch_bounds__(256) void k_transpose_all(const float* __restrict__ w1,
                                                       const float* __restrict__ w3,
                                                       const float* __restrict__ w2,
                                                       bf16* __restrict__ w1t,
                                                       bf16* __restrict__ w3t,
                                                       bf16* __restrict__ w2t) {
    __shared__ float tile[64][65];
    int z = blockIdx.z;
    const float* in = (z == 0) ? w1 : (z == 1) ? w3 : w2;
    bf16* out = (z == 0) ? w1t : (z == 1) ? w3t : w2t;
    int R = (z == 2) ? HID : DIM;
    int C = (z == 2) ? DIM : HID;
    int e = blockIdx.y;
    int ct = C >> 6;
    int r0 = (blockIdx.x / ct) << 6;
    int c0 = (blockIdx.x % ct) << 6;
    const float* src = in + (size_t)e * R * C;
    bf16* dst = out + (size_t)e * R * C;
    int s = threadIdx.x & 15, g = threadIdx.x >> 4;
#pragma unroll
    for (int j = 0; j < 4; ++j) {
        int row = j * 16 + g;
        float4 v = *(const float4*)(src + (size_t)(r0 + row) * C + c0 + s * 4);
        tile[row][s * 4 + 0] = v.x; tile[row][s * 4 + 1] = v.y;
        tile[row][s * 4 + 2] = v.z; tile[row][s * 4 + 3] = v.w;
    }
    __syncthreads();
#pragma unroll
    for (int j = 0; j < 4; ++j) {
        int c = j * 16 + g;
        int r = s * 4;
        bf16 o[4] = {__float2bfloat16(tile[r][c]),     __float2bfloat16(tile[r + 1][c]),
                     __float2bfloat16(tile[r + 2][c]), __float2bfloat16(tile[r + 3][c])};
        *(uint2*)(dst + (size_t)(c0 + c) * R + r0 + r) = *(const uint2*)o;
    }
}

// ------- router logits (fp64 accum) + x->bf16 conversion fused -------
__global__ __launch_bounds__(256) void k_logits(const float* __restrict__ x,
                                                const float* __restrict__ Wr,
                                                float* __restrict__ logits,
                                                bf16* __restrict__ xb) {
    __shared__ float wl[NE][DIM];
    for (int o = threadIdx.x; o < NE * DIM; o += 256) {
        int e = o >> 10, d = o & (DIM - 1);
        wl[e][d] = Wr[d * NE + e];
    }
    __syncthreads();
    int wid = threadIdx.x >> 6, lane = threadIdx.x & 63;
    int t = blockIdx.x * 4 + wid;
    const float* xr = x + (size_t)t * DIM;
    double acc[NE];
#pragma unroll
    for (int e = 0; e < NE; ++e) acc[e] = 0.0;
#pragma unroll
    for (int i = 0; i < DIM / 256; ++i) {
        int base = i * 256 + lane * 4;
        float4 v = *(const float4*)(xr + base);
        bf16 o[4] = {__float2bfloat16(v.x), __float2bfloat16(v.y),
                     __float2bfloat16(v.z), __float2bfloat16(v.w)};
        *(uint2*)(xb + (size_t)t * DIM + base) = *(const uint2*)o;
#pragma unroll
        for (int e = 0; e < NE; ++e)
            acc[e] += (double)v.x * wl[e][base] + (double)v.y * wl[e][base + 1]
                    + (double)v.z * wl[e][base + 2] + (double)v.w * wl[e][base + 3];
    }
#pragma unroll
    for (int e = 0; e < NE; ++e) {
        double v = acc[e];
        for (int m = 32; m >= 1; m >>= 1) v += __shfl_xor(v, m);
        if (lane == 0) logits[t * NE + e] = (float)v;
    }
}

// ---------------- router: softmax, top-2, segment append ----------------
__global__ __launch_bounds__(256) void k_route(const float* __restrict__ logits,
                                               int* counts, int* seg_tok, float* seg_w,
                                               int* slotpos, float* probsum) {
    int t = blockIdx.x * 256 + threadIdx.x;
    float l[NE];
#pragma unroll
    for (int e = 0; e < NE; ++e) l[e] = logits[t * NE + e];
    float mx = l[0];
#pragma unroll
    for (int e = 1; e < NE; ++e) mx = fmaxf(mx, l[e]);
    float p[NE], s = 0.f;
#pragma unroll
    for (int e = 0; e < NE; ++e) { p[e] = expf(l[e] - mx); s += p[e]; }
    float inv = 1.f / s;
#pragma unroll
    for (int e = 0; e < NE; ++e) p[e] *= inv;
    int e0 = 0; float v0 = p[0];
#pragma unroll
    for (int e = 1; e < NE; ++e) if (p[e] > v0) { v0 = p[e]; e0 = e; }
    int e1 = -1; float v1 = -1.f;
#pragma unroll
    for (int e = 0; e < NE; ++e) if (e != e0 && p[e] > v1) { v1 = p[e]; e1 = e; }
    float wsum = v0 + v1;
    float w0 = v0 / wsum, w1 = v1 / wsum;

    int lane = threadIdx.x & 63, wid = threadIdx.x >> 6;
    __shared__ float ps[4][NE];
#pragma unroll
    for (int e = 0; e < NE; ++e) {
        float v = p[e];
        for (int m = 32; m >= 1; m >>= 1) v += __shfl_xor(v, m);
        if (lane == 0) ps[wid][e] = v;
    }
    __syncthreads();
    if (threadIdx.x < NE) {
        float v = ps[0][threadIdx.x] + ps[1][threadIdx.x] + ps[2][threadIdx.x] + ps[3][threadIdx.x];
        atomicAdd(&probsum[threadIdx.x], v);
    }
    for (int slot = 0; slot < 2; ++slot) {
        int   e  = slot ? e1 : e0;
        float wv = slot ? w1 : w0;
#pragma unroll
        for (int ex = 0; ex < NE; ++ex) {
            unsigned long long m = __ballot(e == ex);
            if (e == ex) {
                int leader = __ffsll(m) - 1;
                int base = 0;
                if (lane == leader) base = atomicAdd(&counts[ex], __popcll(m));
                base = __shfl(base, leader);
                int pos = base + (int)__popcll(m & ((1ull << lane) - 1ull));
                if (pos < CAP) {
                    seg_tok[ex * CAP + pos] = t;
                    seg_w[ex * CAP + pos]  = wv;
                    slotpos[2 * t + slot]  = ex * CAP + pos;
                } else {
                    slotpos[2 * t + slot]  = -1;
                }
            }
        }
    }
}

// ======= GEMM1: 128 tok x 128 h, role-split 8 waves (4 g + 4 u), BK=64 =======
// LDS elems: A[128][64] @0, Bg[128][64] @8192, Bu[128][64] @16384 (48KB).
// Row r at panel+r*64; stored chunk c of row r holds source chunk c^(r&7).
// Epilogue: u-exchange + SiLU in LDS [128][128], then coalesced bf16x8 copy-out.
__global__ __launch_bounds__(512, 2) void k_gemm1(const bf16* __restrict__ xb,
                                                  const bf16* __restrict__ w1t,
                                                  const bf16* __restrict__ w3t,
                                                  const int* __restrict__ counts,
                                                  const int* __restrict__ seg_tok,
                                                  bf16* __restrict__ h) {
    __shared__ __align__(16) bf16 lds[24576];
    __shared__ int toks[128];
    const int NTL = HID / 128;                      // 16 ntiles (ntile-fast)
    int flat = blockIdx.y * gridDim.x + blockIdx.x;
    int cpx  = (gridDim.x * NE) >> 3;               // nwg % 8 == 0
    int swz  = (flat & 7) * cpx + (flat >> 3);
    int e    = swz / gridDim.x;
    int tile = swz % gridDim.x;
    int mtile = tile / NTL, ntile = tile % NTL;
    int cnt = counts[e]; if (cnt > CAP) cnt = CAP;
    if (mtile * 128 >= cnt) return;

    int tx = threadIdx.x, lane = tx & 63, w = tx >> 6;
    if (tx < 128) {
        int slot = mtile * 128 + tx;
        toks[tx] = seg_tok[e * CAP + (slot < cnt ? slot : 0)];
    }
    __syncthreads();

    // ---- stage-side: 6 chunks of 512 elems per wave ----
    int l8 = lane >> 3;
    int sch = (((lane & 7) ^ l8) << 3);
    const bf16* sp[6];
    bf16* dp[6];
#pragma unroll
    for (int i = 0; i < 6; ++i) {
        int c = w * 6 + i;
        dp[i] = lds + c * 512 + (lane << 3);
        if (c < 16)
            sp[i] = xb + (size_t)toks[c * 8 + l8] * DIM + sch;
        else if (c < 32)
            sp[i] = w1t + ((size_t)e * HID + ntile * 128 + (c - 16) * 8 + l8) * DIM + sch;
        else
            sp[i] = w3t + ((size_t)e * HID + ntile * 128 + (c - 32) * 8 + l8) * DIM + sch;
    }

    // ---- read-side: 8 waves = role (g/u) x (rh,ch) of 128x128 ----
    int l15 = lane & 15, lh = lane >> 4;
    int role = w >> 2, rh = (w >> 1) & 1, ch = w & 1;
    const int bbase = 8192 + role * 8192;
    f32x4 acc[4][4];
    f32x4 zero4 = {0.f, 0.f, 0.f, 0.f};
#pragma unroll
    for (int m = 0; m < 4; ++m)
#pragma unroll
        for (int n = 0; n < 4; ++n) acc[m][n] = zero4;

    const int NT = DIM / 64;                         // 16 K-iters
#pragma unroll 1
    for (int k = 0; k < NT; ++k) {
        int ko = k * 64;
#pragma unroll
        for (int i = 0; i < 6; ++i) gload16(sp[i] + ko, dp[i]);
        __syncthreads();
#pragma unroll
        for (int ks = 0; ks < 2; ++ks) {
            int co = ((((ks << 2) | lh) ^ (l15 & 7)) << 3);
            bf16x8 af[4], bb[4];
#pragma unroll
            for (int m = 0; m < 4; ++m)
                af[m] = *(const bf16x8*)(lds + (rh * 64 + m * 16 + l15) * 64 + co);
#pragma unroll
            for (int n = 0; n < 4; ++n)
                bb[n] = *(const bf16x8*)(lds + bbase + (ch * 64 + n * 16 + l15) * 64 + co);
#pragma unroll
            for (int n = 0; n < 4; ++n)
#pragma unroll
                for (int m = 0; m < 4; ++m)
                    acc[m][n] = MFMA16(af[m], bb[n], acc[m][n]);
        }
        __syncthreads();
    }

    // ---- epilogue ----
    if (role == 1) {
#pragma unroll
        for (int m = 0; m < 4; ++m)
#pragma unroll
            for (int n = 0; n < 4; ++n)
#pragma unroll
                for (int r = 0; r < 4; ++r) {
                    int row = rh * 64 + m * 16 + lh * 4 + r;
                    int col = ch * 64 + n * 16 + l15;
                    lds[row * 128 + col] = __float2bfloat16(acc[m][n][r]);
                }
    }
    __syncthreads();
    if (role == 0) {
#pragma unroll
        for (int m = 0; m < 4; ++m)
#pragma unroll
            for (int n = 0; n < 4; ++n)
#pragma unroll
                for (int r = 0; r < 4; ++r) {
                    int row = rh * 64 + m * 16 + lh * 4 + r;
                    int col = ch * 64 + n * 16 + l15;
                    float gg = acc[m][n][r];
                    float uu = b2f(*(const unsigned short*)&lds[row * 128 + col]);
                    float hv = gg / (1.f + __expf(-gg)) * uu;
                    lds[row * 128 + col] = __float2bfloat16(hv);
                }
    }
    __syncthreads();
    {
        bf16* hdst = h + ((size_t)e * CAP + (size_t)mtile * 128) * HID + ntile * 128;
#pragma unroll
        for (int j = 0; j < 4; ++j) {
            int idx = tx * 32 + j * 8;              // linear over [0,16384)
            int row = idx >> 7, col = idx & 127;
            *(bf16x8*)(hdst + (size_t)row * HID + col) = *(const bf16x8*)(lds + idx);
        }
    }
}

// ======= GEMM2 (R10 shape): 128 x 128, 4 waves, BK=64, 32KB; LDS-bounce store =======
// LDS elems: A[128][64] @0, B[128][64] @8192.
__global__ __launch_bounds__(256, 3) void k_gemm2(const bf16* __restrict__ hbuf,
                                                  const bf16* __restrict__ w2t,
                                                  const int* __restrict__ counts,
                                                  const float* __restrict__ seg_w,
                                                  bf16* __restrict__ ybuf) {
    __shared__ __align__(16) bf16 lds[16384];
    __shared__ float wts[128];
    const int NTL = DIM / 128;                      // 8 ntiles
    int flat = blockIdx.y * gridDim.x + blockIdx.x;
    int cpx  = (gridDim.x * NE) >> 3;
    int swz  = (flat & 7) * cpx + (flat >> 3);
    int e    = swz / gridDim.x;
    int tile = swz % gridDim.x;
    int mtile = tile / NTL, ntile = tile % NTL;
    int cnt = counts[e]; if (cnt > CAP) cnt = CAP;
    if (mtile * 128 >= cnt) return;

    int tx = threadIdx.x, lane = tx & 63, w = tx >> 6;
    if (tx < 128) {
        int slot = mtile * 128 + tx;
        wts[tx] = (slot < cnt) ? seg_w[e * CAP + slot] : 0.f;
    }
    __syncthreads();

    int l8 = lane >> 3;
    int sch = (((lane & 7) ^ l8) << 3);
    const bf16* sA[4];
    const bf16* sB[4];
#pragma unroll
    for (int i = 0; i < 4; ++i) {
        sA[i] = hbuf + ((size_t)e * CAP + mtile * 128 + w * 32 + i * 8 + l8) * HID + sch;
        sB[i] = w2t + ((size_t)e * DIM + ntile * 128 + w * 32 + i * 8 + l8) * HID + sch;
    }
    bf16* dA = lds + w * 2048 + (lane << 3);             // + i*512
    bf16* dB = lds + 8192 + w * 2048 + (lane << 3);      // + i*512

    int l15 = lane & 15, lh = lane >> 4;
    int wm = w >> 1, wn = w & 1;                     // wave = 64 x 64
    f32x4 acc[4][4];
    f32x4 zero4 = {0.f, 0.f, 0.f, 0.f};
#pragma unroll
    for (int m = 0; m < 4; ++m)
#pragma unroll
        for (int n = 0; n < 4; ++n) acc[m][n] = zero4;

    const int NT = HID / 64;                         // 32 K-iters
#pragma unroll 1
    for (int k = 0; k < NT; ++k) {
        int ko = k * 64;
#pragma unroll
        for (int i = 0; i < 4; ++i) {
            gload16(sA[i] + ko, dA + i * 512);
            gload16(sB[i] + ko, dB + i * 512);
        }
        __syncthreads();
#pragma unroll
        for (int ks = 0; ks < 2; ++ks) {
            int co = ((((ks << 2) | lh) ^ (l15 & 7)) << 3);
            bf16x8 af[4], bf_[4];
#pragma unroll
            for (int m = 0; m < 4; ++m) {
                int row = wm * 64 + m * 16 + l15;
                af[m] = *(const bf16x8*)(lds + row * 64 + co);
                int br = wn * 64 + m * 16 + l15;
                bf_[m] = *(const bf16x8*)(lds + 8192 + br * 64 + co);
            }
#pragma unroll
            for (int n = 0; n < 4; ++n)
#pragma unroll
                for (int m = 0; m < 4; ++m)
                    acc[m][n] = MFMA16(af[m], bf_[n], acc[m][n]);
        }
        __syncthreads();
    }

    // ---- epilogue: scaled bf16 into LDS [128][128], coalesced copy-out ----
#pragma unroll
    for (int m = 0; m < 4; ++m)
#pragma unroll
        for (int n = 0; n < 4; ++n)
#pragma unroll
            for (int r = 0; r < 4; ++r) {
                int row = wm * 64 + m * 16 + lh * 4 + r;
                int col = wn * 64 + n * 16 + l15;
                lds[row * 128 + col] = __float2bfloat16(acc[m][n][r] * wts[row]);
            }
    __syncthreads();
    {
        bf16* ydst = ybuf + ((size_t)e * CAP + (size_t)mtile * 128) * DIM + ntile * 128;
#pragma unroll
        for (int j = 0; j < 8; ++j) {
            int idx = tx * 64 + j * 8;              // linear over [0,16384)
            int row = idx >> 7, col = idx & 127;
            *(bf16x8*)(ydst + (size_t)row * DIM + col) = *(const bf16x8*)(lds + idx);
        }
    }
}

// ------- combine: out[t] = ybuf[slot0] + ybuf[slot1]; block 0 also does aux -------
__global__ __launch_bounds__(256) void k_combine(const bf16* __restrict__ yb,
                                                 const int* __restrict__ slotpos,
                                                 const int* __restrict__ counts,
                                                 const float* __restrict__ probsum,
                                                 float* __restrict__ out) {
    int t = blockIdx.x;
    int s0 = slotpos[2 * t], s1 = slotpos[2 * t + 1];
    int d = threadIdx.x * 4;
    float4 a = {0.f, 0.f, 0.f, 0.f};
    if (s0 >= 0) {
        ushort4 v = *(const ushort4*)(yb + (size_t)s0 * DIM + d);
        a.x += b2f(v.x); a.y += b2f(v.y); a.z += b2f(v.z); a.w += b2f(v.w);
    }
    if (s1 >= 0) {
        ushort4 v = *(const ushort4*)(yb + (size_t)s1 * DIM + d);
        a.x += b2f(v.x); a.y += b2f(v.y); a.z += b2f(v.z); a.w += b2f(v.w);
    }
    *(float4*)(out + (size_t)t * DIM + d) = a;
    if (t == 0 && threadIdx.x == 0) {
        float s = 0.f;
        for (int e = 0; e < NE; ++e)
            s += ((float)counts[e] / (float)T_TOK) * (probsum[e] / (float)T_TOK);
        out[(size_t)T_TOK * DIM] = (float)NE * s;
    }
}

extern "C" void kernel_launch(void* const* d_in, const int* in_sizes, int n_in,
                              void* d_out, int out_size, void* d_ws, size_t ws_size,
                              hipStream_t stream) {
    const float* x  = (const float*)d_in[0];
    const float* Wr = (const float*)d_in[1];
    const float* w1 = (const float*)d_in[2];
    const float* w2 = (const float*)d_in[3];
    const float* w3 = (const float*)d_in[4];
    float* out = (float*)d_out;

    char* ws = (char*)d_ws;
    size_t off = 0;
    auto alloc = [&](size_t bytes) { void* p = ws + off; off += (bytes + 255) & ~(size_t)255; return p; };
    bf16*  xb      = (bf16*)alloc((size_t)T_TOK * DIM * 2);
    bf16*  w1t     = (bf16*)alloc((size_t)NE * HID * DIM * 2);
    bf16*  w3t     = (bf16*)alloc((size_t)NE * HID * DIM * 2);
    bf16*  w2t     = (bf16*)alloc((size_t)NE * DIM * HID * 2);
    bf16*  hbuf    = (bf16*)alloc((size_t)NE * CAP * HID * 2);
    float* logits  = (float*)alloc((size_t)T_TOK * NE * 4);
    int*   counts  = (int*)alloc(256);
    int*   segtok  = (int*)alloc((size_t)NE * CAP * 4);
    float* segw    = (float*)alloc((size_t)NE * CAP * 4);
    int*   slotpos = (int*)alloc((size_t)T_TOK * 2 * 4);
    float* probsum = (float*)alloc(256);
    // ybuf reuses w1t+w3t (dead after k_gemm1): 46.1 MB < 67.1 MB available
    bf16*  ybuf    = w1t;
    (void)ws_size; (void)in_sizes; (void)n_in;

    hipMemsetAsync(counts, 0, 256, stream);
    hipMemsetAsync(probsum, 0, 256, stream);

    k_logits<<<T_TOK / 4, 256, 0, stream>>>(x, Wr, logits, xb);
    k_route<<<T_TOK / 256, 256, 0, stream>>>(logits, counts, segtok, segw, slotpos, probsum);

    dim3 gt((DIM / 64) * (HID / 64), NE, 3);
    k_transpose_all<<<gt, 256, 0, stream>>>(w1, w3, w2, w1t, w3t, w2t);

    dim3 g1((CAP / 128) * (HID / 128), NE);    // 22*16=352 x 8 = 2816, %8==0
    k_gemm1<<<g1, 512, 0, stream>>>(xb, w1t, w3t, counts, segtok, hbuf);
    dim3 g2((CAP / 128) * (DIM / 128), NE);    // 22*8=176 x 8 = 1408, %8==0
    k_gemm2<<<g2, 256, 0, stream>>>(hbuf, w2t, counts, segw, ybuf);

    k_combine<<<T_TOK, 256, 0, stream>>>(ybuf, slotpos, counts, probsum, out);
}

// Round 13
// 378.127 us; speedup vs baseline: 1.0595x; 1.0595x over previous
//
#include <hip/hip_runtime.h>
#include <hip/hip_bf16.h>
#include <cstdint>
#include <cstddef>

#define T_TOK 8192
#define DIM   1024
#define HID   2048
#define NE    8
#define CAP   2816   // 22 tiles of 128; expected count ~2048, +19 sigma margin

typedef __attribute__((ext_vector_type(8))) short bf16x8;
typedef __attribute__((ext_vector_type(4))) float f32x4;
using bf16 = __hip_bfloat16;

__device__ __forceinline__ void gload16(const bf16* g, bf16* l) {
    __builtin_amdgcn_global_load_lds(
        (const __attribute__((address_space(1))) unsigned int*)(g),
        (__attribute__((address_space(3))) unsigned int*)(l), 16, 0, 0);
}
__device__ __forceinline__ float b2f(unsigned short u) {
    return __uint_as_float(((unsigned int)u) << 16);
}
#define MFMA16(a, b, c) __builtin_amdgcn_mfma_f32_16x16x32_bf16((a), (b), (c), 0, 0, 0)

// ---- fused per-expert transpose+convert: [E][R][C] f32 -> [E][C][R] bf16 ----
__global__ __launch_bounds__(256) void k_transpose_all(const float* __restrict__ w1,
                                                       const float* __restrict__ w3,
                                                       const float* __restrict__ w2,
                                                       bf16* __restrict__ w1t,
                                                       bf16* __restrict__ w3t,
                                                       bf16* __restrict__ w2t) {
    __shared__ float tile[64][65];
    int z = blockIdx.z;
    const float* in = (z == 0) ? w1 : (z == 1) ? w3 : w2;
    bf16* out = (z == 0) ? w1t : (z == 1) ? w3t : w2t;
    int R = (z == 2) ? HID : DIM;
    int C = (z == 2) ? DIM : HID;
    int e = blockIdx.y;
    int ct = C >> 6;
    int r0 = (blockIdx.x / ct) << 6;
    int c0 = (blockIdx.x % ct) << 6;
    const float* src = in + (size_t)e * R * C;
    bf16* dst = out + (size_t)e * R * C;
    int s = threadIdx.x & 15, g = threadIdx.x >> 4;
#pragma unroll
    for (int j = 0; j < 4; ++j) {
        int row = j * 16 + g;
        float4 v = *(const float4*)(src + (size_t)(r0 + row) * C + c0 + s * 4);
        tile[row][s * 4 + 0] = v.x; tile[row][s * 4 + 1] = v.y;
        tile[row][s * 4 + 2] = v.z; tile[row][s * 4 + 3] = v.w;
    }
    __syncthreads();
#pragma unroll
    for (int j = 0; j < 4; ++j) {
        int c = j * 16 + g;
        int r = s * 4;
        bf16 o[4] = {__float2bfloat16(tile[r][c]),     __float2bfloat16(tile[r + 1][c]),
                     __float2bfloat16(tile[r + 2][c]), __float2bfloat16(tile[r + 3][c])};
        *(uint2*)(dst + (size_t)(c0 + c) * R + r0 + r) = *(const uint2*)o;
    }
}

// ------- router logits (fp64 accum) + x->bf16 conversion fused -------
__global__ __launch_bounds__(256) void k_logits(const float* __restrict__ x,
                                                const float* __restrict__ Wr,
                                                float* __restrict__ logits,
                                                bf16* __restrict__ xb) {
    __shared__ float wl[NE][DIM];
    for (int o = threadIdx.x; o < NE * DIM; o += 256) {
        int e = o >> 10, d = o & (DIM - 1);
        wl[e][d] = Wr[d * NE + e];
    }
    __syncthreads();
    int wid = threadIdx.x >> 6, lane = threadIdx.x & 63;
    int t = blockIdx.x * 4 + wid;
    const float* xr = x + (size_t)t * DIM;
    double acc[NE];
#pragma unroll
    for (int e = 0; e < NE; ++e) acc[e] = 0.0;
#pragma unroll
    for (int i = 0; i < DIM / 256; ++i) {
        int base = i * 256 + lane * 4;
        float4 v = *(const float4*)(xr + base);
        bf16 o[4] = {__float2bfloat16(v.x), __float2bfloat16(v.y),
                     __float2bfloat16(v.z), __float2bfloat16(v.w)};
        *(uint2*)(xb + (size_t)t * DIM + base) = *(const uint2*)o;
#pragma unroll
        for (int e = 0; e < NE; ++e)
            acc[e] += (double)v.x * wl[e][base] + (double)v.y * wl[e][base + 1]
                    + (double)v.z * wl[e][base + 2] + (double)v.w * wl[e][base + 3];
    }
#pragma unroll
    for (int e = 0; e < NE; ++e) {
        double v = acc[e];
        for (int m = 32; m >= 1; m >>= 1) v += __shfl_xor(v, m);
        if (lane == 0) logits[t * NE + e] = (float)v;
    }
}

// ---------------- router: softmax, top-2, segment append ----------------
__global__ __launch_bounds__(256) void k_route(const float* __restrict__ logits,
                                               int* counts, int* seg_tok, float* seg_w,
                                               int* slotpos, float* probsum) {
    int t = blockIdx.x * 256 + threadIdx.x;
    float l[NE];
#pragma unroll
    for (int e = 0; e < NE; ++e) l[e] = logits[t * NE + e];
    float mx = l[0];
#pragma unroll
    for (int e = 1; e < NE; ++e) mx = fmaxf(mx, l[e]);
    float p[NE], s = 0.f;
#pragma unroll
    for (int e = 0; e < NE; ++e) { p[e] = expf(l[e] - mx); s += p[e]; }
    float inv = 1.f / s;
#pragma unroll
    for (int e = 0; e < NE; ++e) p[e] *= inv;
    int e0 = 0; float v0 = p[0];
#pragma unroll
    for (int e = 1; e < NE; ++e) if (p[e] > v0) { v0 = p[e]; e0 = e; }
    int e1 = -1; float v1 = -1.f;
#pragma unroll
    for (int e = 0; e < NE; ++e) if (e != e0 && p[e] > v1) { v1 = p[e]; e1 = e; }
    float wsum = v0 + v1;
    float w0 = v0 / wsum, w1 = v1 / wsum;

    int lane = threadIdx.x & 63, wid = threadIdx.x >> 6;
    __shared__ float ps[4][NE];
#pragma unroll
    for (int e = 0; e < NE; ++e) {
        float v = p[e];
        for (int m = 32; m >= 1; m >>= 1) v += __shfl_xor(v, m);
        if (lane == 0) ps[wid][e] = v;
    }
    __syncthreads();
    if (threadIdx.x < NE) {
        float v = ps[0][threadIdx.x] + ps[1][threadIdx.x] + ps[2][threadIdx.x] + ps[3][threadIdx.x];
        atomicAdd(&probsum[threadIdx.x], v);
    }
    for (int slot = 0; slot < 2; ++slot) {
        int   e  = slot ? e1 : e0;
        float wv = slot ? w1 : w0;
#pragma unroll
        for (int ex = 0; ex < NE; ++ex) {
            unsigned long long m = __ballot(e == ex);
            if (e == ex) {
                int leader = __ffsll(m) - 1;
                int base = 0;
                if (lane == leader) base = atomicAdd(&counts[ex], __popcll(m));
                base = __shfl(base, leader);
                int pos = base + (int)__popcll(m & ((1ull << lane) - 1ull));
                if (pos < CAP) {
                    seg_tok[ex * CAP + pos] = t;
                    seg_w[ex * CAP + pos]  = wv;
                    slotpos[2 * t + slot]  = ex * CAP + pos;
                } else {
                    slotpos[2 * t + slot]  = -1;
                }
            }
        }
    }
}

// ======= GEMM1 (R11 config): 128 tok x 128 h, role-split 8 waves, BK=64 =======
// LDS elems: A[128][64] @0, Bg[128][64] @8192, Bu[128][64] @16384 (48KB).
// Row r at panel+r*64; stored chunk c of row r holds source chunk c^(r&7).
__global__ __launch_bounds__(512, 2) void k_gemm1(const bf16* __restrict__ xb,
                                                  const bf16* __restrict__ w1t,
                                                  const bf16* __restrict__ w3t,
                                                  const int* __restrict__ counts,
                                                  const int* __restrict__ seg_tok,
                                                  bf16* __restrict__ h) {
    __shared__ __align__(16) bf16 lds[24576];
    __shared__ int toks[128];
    const int NTL = HID / 128;                      // 16 ntiles (ntile-fast)
    int flat = blockIdx.y * gridDim.x + blockIdx.x;
    int cpx  = (gridDim.x * NE) >> 3;               // nwg % 8 == 0
    int swz  = (flat & 7) * cpx + (flat >> 3);
    int e    = swz / gridDim.x;
    int tile = swz % gridDim.x;
    int mtile = tile / NTL, ntile = tile % NTL;
    int cnt = counts[e]; if (cnt > CAP) cnt = CAP;
    if (mtile * 128 >= cnt) return;

    int tx = threadIdx.x, lane = tx & 63, w = tx >> 6;
    if (tx < 128) {
        int slot = mtile * 128 + tx;
        toks[tx] = seg_tok[e * CAP + (slot < cnt ? slot : 0)];
    }
    __syncthreads();

    // ---- stage-side: 6 chunks of 512 elems per wave ----
    int l8 = lane >> 3;
    int sch = (((lane & 7) ^ l8) << 3);
    const bf16* sp[6];
    bf16* dp[6];
#pragma unroll
    for (int i = 0; i < 6; ++i) {
        int c = w * 6 + i;
        dp[i] = lds + c * 512 + (lane << 3);
        if (c < 16)
            sp[i] = xb + (size_t)toks[c * 8 + l8] * DIM + sch;
        else if (c < 32)
            sp[i] = w1t + ((size_t)e * HID + ntile * 128 + (c - 16) * 8 + l8) * DIM + sch;
        else
            sp[i] = w3t + ((size_t)e * HID + ntile * 128 + (c - 32) * 8 + l8) * DIM + sch;
    }

    // ---- read-side: 8 waves = role (g/u) x (rh,ch) of 128x128 ----
    int l15 = lane & 15, lh = lane >> 4;
    int role = w >> 2, rh = (w >> 1) & 1, ch = w & 1;
    const int bbase = 8192 + role * 8192;
    f32x4 acc[4][4];
    f32x4 zero4 = {0.f, 0.f, 0.f, 0.f};
#pragma unroll
    for (int m = 0; m < 4; ++m)
#pragma unroll
        for (int n = 0; n < 4; ++n) acc[m][n] = zero4;

    const int NT = DIM / 64;                         // 16 K-iters
#pragma unroll 1
    for (int k = 0; k < NT; ++k) {
        int ko = k * 64;
#pragma unroll
        for (int i = 0; i < 6; ++i) gload16(sp[i] + ko, dp[i]);
        __syncthreads();
#pragma unroll
        for (int ks = 0; ks < 2; ++ks) {
            int co = ((((ks << 2) | lh) ^ (l15 & 7)) << 3);
            bf16x8 af[4], bb[4];
#pragma unroll
            for (int m = 0; m < 4; ++m)
                af[m] = *(const bf16x8*)(lds + (rh * 64 + m * 16 + l15) * 64 + co);
#pragma unroll
            for (int n = 0; n < 4; ++n)
                bb[n] = *(const bf16x8*)(lds + bbase + (ch * 64 + n * 16 + l15) * 64 + co);
#pragma unroll
            for (int n = 0; n < 4; ++n)
#pragma unroll
                for (int m = 0; m < 4; ++m)
                    acc[m][n] = MFMA16(af[m], bb[n], acc[m][n]);
        }
        __syncthreads();
    }

    // epilogue: u-waves deposit bf16 to LDS [128][128]; g-waves fuse SiLU and store
    if (role == 1) {
#pragma unroll
        for (int m = 0; m < 4; ++m)
#pragma unroll
            for (int n = 0; n < 4; ++n)
#pragma unroll
                for (int r = 0; r < 4; ++r) {
                    int row = rh * 64 + m * 16 + lh * 4 + r;
                    int col = ch * 64 + n * 16 + l15;
                    lds[row * 128 + col] = __float2bfloat16(acc[m][n][r]);
                }
    }
    __syncthreads();
    if (role == 0) {
        bf16* hdst = h + ((size_t)e * CAP + (size_t)mtile * 128) * HID + ntile * 128;
#pragma unroll
        for (int m = 0; m < 4; ++m)
#pragma unroll
            for (int n = 0; n < 4; ++n)
#pragma unroll
                for (int r = 0; r < 4; ++r) {
                    int row = rh * 64 + m * 16 + lh * 4 + r;
                    int col = ch * 64 + n * 16 + l15;
                    float gg = acc[m][n][r];
                    float uu = b2f(*(const unsigned short*)&lds[row * 128 + col]);
                    float hv = gg / (1.f + __expf(-gg)) * uu;
                    hdst[(size_t)row * HID + col] = __float2bfloat16(hv);
                }
    }
}

// ======= GEMM2 (R10 config): 128 x 128, 4 waves, BK=64, 32KB; direct store =======
// LDS elems: A[128][64] @0, B[128][64] @8192.
__global__ __launch_bounds__(256, 3) void k_gemm2(const bf16* __restrict__ hbuf,
                                                  const bf16* __restrict__ w2t,
                                                  const int* __restrict__ counts,
                                                  const float* __restrict__ seg_w,
                                                  bf16* __restrict__ ybuf) {
    __shared__ __align__(16) bf16 lds[16384];
    __shared__ float wts[128];
    const int NTL = DIM / 128;                      // 8 ntiles
    int flat = blockIdx.y * gridDim.x + blockIdx.x;
    int cpx  = (gridDim.x * NE) >> 3;
    int swz  = (flat & 7) * cpx + (flat >> 3);
    int e    = swz / gridDim.x;
    int tile = swz % gridDim.x;
    int mtile = tile / NTL, ntile = tile % NTL;
    int cnt = counts[e]; if (cnt > CAP) cnt = CAP;
    if (mtile * 128 >= cnt) return;

    int tx = threadIdx.x, lane = tx & 63, w = tx >> 6;
    if (tx < 128) {
        int slot = mtile * 128 + tx;
        wts[tx] = (slot < cnt) ? seg_w[e * CAP + slot] : 0.f;
    }
    __syncthreads();

    int l8 = lane >> 3;
    int sch = (((lane & 7) ^ l8) << 3);
    const bf16* sA[4];
    const bf16* sB[4];
#pragma unroll
    for (int i = 0; i < 4; ++i) {
        sA[i] = hbuf + ((size_t)e * CAP + mtile * 128 + w * 32 + i * 8 + l8) * HID + sch;
        sB[i] = w2t + ((size_t)e * DIM + ntile * 128 + w * 32 + i * 8 + l8) * HID + sch;
    }
    bf16* dA = lds + w * 2048 + (lane << 3);             // + i*512
    bf16* dB = lds + 8192 + w * 2048 + (lane << 3);      // + i*512

    int l15 = lane & 15, lh = lane >> 4;
    int wm = w >> 1, wn = w & 1;                     // wave = 64 x 64
    f32x4 acc[4][4];
    f32x4 zero4 = {0.f, 0.f, 0.f, 0.f};
#pragma unroll
    for (int m = 0; m < 4; ++m)
#pragma unroll
        for (int n = 0; n < 4; ++n) acc[m][n] = zero4;

    const int NT = HID / 64;                         // 32 K-iters
#pragma unroll 1
    for (int k = 0; k < NT; ++k) {
        int ko = k * 64;
#pragma unroll
        for (int i = 0; i < 4; ++i) {
            gload16(sA[i] + ko, dA + i * 512);
            gload16(sB[i] + ko, dB + i * 512);
        }
        __syncthreads();
#pragma unroll
        for (int ks = 0; ks < 2; ++ks) {
            int co = ((((ks << 2) | lh) ^ (l15 & 7)) << 3);
            bf16x8 af[4], bf_[4];
#pragma unroll
            for (int m = 0; m < 4; ++m) {
                int row = wm * 64 + m * 16 + l15;
                af[m] = *(const bf16x8*)(lds + row * 64 + co);
                int br = wn * 64 + m * 16 + l15;
                bf_[m] = *(const bf16x8*)(lds + 8192 + br * 64 + co);
            }
#pragma unroll
            for (int n = 0; n < 4; ++n)
#pragma unroll
                for (int m = 0; m < 4; ++m)
                    acc[m][n] = MFMA16(af[m], bf_[n], acc[m][n]);
        }
        __syncthreads();
    }

    bf16* ydst = ybuf + ((size_t)e * CAP + (size_t)mtile * 128) * DIM + ntile * 128;
#pragma unroll
    for (int m = 0; m < 4; ++m)
#pragma unroll
        for (int n = 0; n < 4; ++n)
#pragma unroll
            for (int r = 0; r < 4; ++r) {
                int row = wm * 64 + m * 16 + lh * 4 + r;
                int col = wn * 64 + n * 16 + l15;
                ydst[(size_t)row * DIM + col] = __float2bfloat16(acc[m][n][r] * wts[row]);
            }
}

// ------- combine: out[t] = ybuf[slot0] + ybuf[slot1]; block 0 also does aux -------
__global__ __launch_bounds__(256) void k_combine(const bf16* __restrict__ yb,
                                                 const int* __restrict__ slotpos,
                                                 const int* __restrict__ counts,
                                                 const float* __restrict__ probsum,
                                                 float* __restrict__ out) {
    int t = blockIdx.x;
    int s0 = slotpos[2 * t], s1 = slotpos[2 * t + 1];
    int d = threadIdx.x * 4;
    float4 a = {0.f, 0.f, 0.f, 0.f};
    if (s0 >= 0) {
        ushort4 v = *(const ushort4*)(yb + (size_t)s0 * DIM + d);
        a.x += b2f(v.x); a.y += b2f(v.y); a.z += b2f(v.z); a.w += b2f(v.w);
    }
    if (s1 >= 0) {
        ushort4 v = *(const ushort4*)(yb + (size_t)s1 * DIM + d);
        a.x += b2f(v.x); a.y += b2f(v.y); a.z += b2f(v.z); a.w += b2f(v.w);
    }
    *(float4*)(out + (size_t)t * DIM + d) = a;
    if (t == 0 && threadIdx.x == 0) {
        float s = 0.f;
        for (int e = 0; e < NE; ++e)
            s += ((float)counts[e] / (float)T_TOK) * (probsum[e] / (float)T_TOK);
        out[(size_t)T_TOK * DIM] = (float)NE * s;
    }
}

extern "C" void kernel_launch(void* const* d_in, const int* in_sizes, int n_in,
                              void* d_out, int out_size, void* d_ws, size_t ws_size,
                              hipStream_t stream) {
    const float* x  = (const float*)d_in[0];
    const float* Wr = (const float*)d_in[1];
    const float* w1 = (const float*)d_in[2];
    const float* w2 = (const float*)d_in[3];
    const float* w3 = (const float*)d_in[4];
    float* out = (float*)d_out;

    char* ws = (char*)d_ws;
    size_t off = 0;
    auto alloc = [&](size_t bytes) { void* p = ws + off; off += (bytes + 255) & ~(size_t)255; return p; };
    bf16*  xb      = (bf16*)alloc((size_t)T_TOK * DIM * 2);
    bf16*  w1t     = (bf16*)alloc((size_t)NE * HID * DIM * 2);
    bf16*  w3t     = (bf16*)alloc((size_t)NE * HID * DIM * 2);
    bf16*  w2t     = (bf16*)alloc((size_t)NE * DIM * HID * 2);
    bf16*  hbuf    = (bf16*)alloc((size_t)NE * CAP * HID * 2);
    float* logits  = (float*)alloc((size_t)T_TOK * NE * 4);
    int*   counts  = (int*)alloc(256);
    int*   segtok  = (int*)alloc((size_t)NE * CAP * 4);
    float* segw    = (float*)alloc((size_t)NE * CAP * 4);
    int*   slotpos = (int*)alloc((size_t)T_TOK * 2 * 4);
    float* probsum = (float*)alloc(256);
    // ybuf reuses w1t+w3t (dead after k_gemm1): 46.1 MB < 67.1 MB available
    bf16*  ybuf    = w1t;
    (void)ws_size; (void)in_sizes; (void)n_in;

    hipMemsetAsync(counts, 0, 256, stream);
    hipMemsetAsync(probsum, 0, 256, stream);

    k_logits<<<T_TOK / 4, 256, 0, stream>>>(x, Wr, logits, xb);
    k_route<<<T_TOK / 256, 256, 0, stream>>>(logits, counts, segtok, segw, slotpos, probsum);

    dim3 gt((DIM / 64) * (HID / 64), NE, 3);
    k_transpose_all<<<gt, 256, 0, stream>>>(w1, w3, w2, w1t, w3t, w2t);

    dim3 g1((CAP / 128) * (HID / 128), NE);    // 22*16=352 x 8 = 2816, %8==0
    k_gemm1<<<g1, 512, 0, stream>>>(xb, w1t, w3t, counts, segtok, hbuf);
    dim3 g2((CAP / 128) * (DIM / 128), NE);    // 22*8=176 x 8 = 1408, %8==0
    k_gemm2<<<g2, 256, 0, stream>>>(hbuf, w2t, counts, segw, ybuf);

    k_combine<<<T_TOK, 256, 0, stream>>>(ybuf, slotpos, counts, probsum, out);
}